// Round 6
// baseline (333.679 us; speedup 1.0000x reference)
//
#include <hip/hip_runtime.h>
#include <hip/hip_bf16.h>
#include <math.h>

// Problem constants
#define B 16
#define S 4096
#define D 64
#define NH 8
#define NBUCK 64          // buckets per hash
#define CHUNKS 512        // chunks per batch (NH * NBUCK)
#define BS 64             // bucket/chunk size

typedef __attribute__((ext_vector_type(8))) short s8_t;   // 8 bf16 (4 VGPRs)
typedef __attribute__((ext_vector_type(4))) float f4_t;   // MFMA C/D

// truncation-pack two f32 into (bf16(x0) | bf16(x1)<<16): one v_perm_b32
__device__ inline unsigned int pack_trunc(float x0, float x1) {
    return __builtin_amdgcn_perm(__float_as_uint(x1), __float_as_uint(x0),
                                 0x07060302u);
}
__device__ inline unsigned short bf16_trunc(float x) {
    return (unsigned short)(__float_as_uint(x) >> 16);
}

// ---------------------------------------------------------------------------
// Kernel 1: hashing (f64). Register-blocked 8 tokens/lane x 8 outputs x 4
// passes. FMA order per (token,output) over f is identical to all prior
// rounds -> bit-identical buckets. R-traffic halved vs R4 (256 dbl/token).
// ---------------------------------------------------------------------------
__global__ __launch_bounds__(256, 1) void hash_kernel(
    const float* __restrict__ qk, const float* __restrict__ rot,
    float* __restrict__ out_buckets, int* __restrict__ bucket_ws)
{
    __shared__ double R[64 * 32];   // R[f*32+i], 16 KB
    int tid = threadIdx.x;
    int bid = blockIdx.x;
    int b   = bid >> 4;
    int h   = (bid >> 1) & 7;
    int halfidx = bid & 1;

    for (int e = tid; e < 2048; e += 256) {
        int f = e >> 5, i = e & 31;
        R[e] = (double)rot[f * (NH * 32) + h * 32 + i];
    }
    __syncthreads();

    const float4* base4 = (const float4*)(qk + (size_t)b * S * D);

    double bestv[8], worstv[8];
    int bi[8], wi[8];

    for (int p = 0; p < 4; ++p) {
        double acc[64];   // acc[i*8+j], i in 0..7 (outputs p*8+i), j tokens
        #pragma unroll
        for (int e = 0; e < 64; ++e) acc[e] = 0.0;

        for (int fc = 0; fc < 16; ++fc) {
            float xf[8][4];
            #pragma unroll
            for (int j = 0; j < 8; ++j) {
                int t = halfidx * 2048 + j * 256 + tid;
                float4 x4 = base4[t * 16 + fc];
                xf[j][0] = x4.x; xf[j][1] = x4.y; xf[j][2] = x4.z; xf[j][3] = x4.w;
            }
            #pragma unroll
            for (int u = 0; u < 4; ++u) {
                int f = fc * 4 + u;
                const double2* Rr = (const double2*)&R[f * 32 + p * 8];
                double xd[8];
                #pragma unroll
                for (int j = 0; j < 8; ++j) xd[j] = (double)xf[j][u];
                #pragma unroll
                for (int ii = 0; ii < 4; ++ii) {
                    double2 r2 = Rr[ii];
                    #pragma unroll
                    for (int j = 0; j < 8; ++j) {
                        acc[(2*ii)*8 + j]   = __fma_rn(xd[j], r2.x, acc[(2*ii)*8 + j]);
                        acc[(2*ii+1)*8 + j] = __fma_rn(xd[j], r2.y, acc[(2*ii+1)*8 + j]);
                    }
                }
            }
        }
        #pragma unroll
        for (int i = 0; i < 8; ++i) {
            int gi = p * 8 + i;
            #pragma unroll
            for (int j = 0; j < 8; ++j) {
                double vv = acc[i*8 + j];
                if (p == 0 && i == 0) {
                    bestv[j] = vv; bi[j] = 0; worstv[j] = vv; wi[j] = 0;
                } else {
                    if (vv > bestv[j])  { bestv[j] = vv; bi[j] = gi; }
                    if (vv < worstv[j]) { worstv[j] = vv; wi[j] = gi; }
                }
            }
        }
    }

    #pragma unroll
    for (int j = 0; j < 8; ++j) {
        int t = halfidx * 2048 + j * 256 + tid;
        int bucket = (-worstv[j] > bestv[j]) ? (32 + wi[j]) : bi[j];
        size_t idx = (size_t)(b * NH + h) * S + t;
        bucket_ws[idx] = bucket;
        out_buckets[idx] = (float)(bucket + h * NBUCK);
    }
}

// ---------------------------------------------------------------------------
// Kernel 2: parallel stable counting sort per (b,h). 256 threads (4 waves).
// ---------------------------------------------------------------------------
__global__ __launch_bounds__(256) void sort_kernel(
    const int* __restrict__ bucket_ws, int* __restrict__ st_ws)
{
    __shared__ int sb[S];
    __shared__ int hist[4][64];
    __shared__ int bpref[64];
    __shared__ int woff[4][64];

    int tid  = threadIdx.x;
    int wv   = tid >> 6;
    int lane = tid & 63;
    int base = blockIdx.x * S;

    hist[wv][lane] = 0;
    __syncthreads();

    int qbase = wv * 1024;
    #pragma unroll
    for (int i = 0; i < 16; ++i) {
        int t = qbase + i * 64 + lane;
        int v = bucket_ws[base + t];
        sb[t] = v;
        atomicAdd(&hist[wv][v], 1);
    }
    __syncthreads();

    if (wv == 0) {
        int total = hist[0][lane] + hist[1][lane] + hist[2][lane] + hist[3][lane];
        int x = total;
        #pragma unroll
        for (int off = 1; off < 64; off <<= 1) {
            int y = __shfl_up(x, off, 64);
            if (lane >= off) x += y;
        }
        bpref[lane] = x - total;
    }
    __syncthreads();
    {
        int o = bpref[lane];
        for (int w2 = 0; w2 < 4; ++w2) {
            if (w2 < wv) o += hist[w2][lane];
        }
        woff[wv][lane] = o;
    }
    __syncthreads();

    for (int g = 0; g < 16; ++g) {
        int t = qbase + g * 64 + lane;
        int v = sb[t];

        unsigned long long m = ~0ULL;
        #pragma unroll
        for (int bit = 0; bit < 6; ++bit) {
            unsigned long long bm = __ballot((v >> bit) & 1);
            m &= ((v >> bit) & 1) ? bm : ~bm;
        }
        unsigned long long below = (lane == 63) ? ~0ULL >> 1
                                 : ((1ULL << lane) - 1ULL);
        int rank = __popcll(m & below);
        int cnt  = __popcll(m);

        int pos = woff[wv][v] + rank;
        st_ws[base + pos] = t;

        if ((m & below) == 0ULL)
            woff[wv][v] += cnt;
        __builtin_amdgcn_s_waitcnt(0);
    }
}

// ---------------------------------------------------------------------------
// Kernel 3: per-chunk attention, plain-bf16 MFMA, truncation-packed converts.
// LDS layout (37888 B -> 4 blocks/CU):
//   K  [128 rows][144 B] @0      (18432)  normalized keys bf16
//                                 -- rows 0..63 overlaid by P[64][144B] post-dots
//   VtP[64 rows][288 B]  @18432  (18432)  V^T packed: dword = keys(2a,2a+1)
//   nrm @36864 (512), tkx @37376 (512)
// ---------------------------------------------------------------------------
#define OFF_VT 18432
#define OFF_NRM 36864
#define OFF_TKX 37376
#define LDS_TOT 37888
#define KSTRB 144     // K/P row stride bytes (72 bf16), 16B-aligned
#define VSTRD 72      // VtP row stride in dwords (288 B)

__global__ __launch_bounds__(256, 4) void attn_kernel(
    const float* __restrict__ qk, const float* __restrict__ v,
    const int* __restrict__ st_ws,
    __hip_bfloat16* __restrict__ o_ws, float* __restrict__ logits_ws)
{
    __shared__ char lds[LDS_TOT];
    float* nrm_s = (float*)(lds + OFF_NRM);
    int*   tkx   = (int*)(lds + OFF_TKX);
    unsigned int* VtP = (unsigned int*)(lds + OFF_VT);

    int tid = threadIdx.x;
    int c = blockIdx.x & (CHUNKS - 1);
    int b = blockIdx.x >> 9;
    int h = c >> 6;
    int sbase = b * (NH * S);

    if (tid < 128) {
        int cc2 = (tid < 64) ? c : ((c + CHUNKS - 1) & (CHUNKS - 1));
        tkx[tid] = st_ws[sbase + cc2 * BS + (tid & 63)];
    }
    __syncthreads();

    // ---- stage K (normalized bf16, row-major) ----
    {
        int r = tid >> 1, half = tid & 1;
        int tok = tkx[r];
        const float4* qs = (const float4*)(qk + ((size_t)b * S + tok) * D) + half * 8;
        float xq[32];
        #pragma unroll
        for (int e4 = 0; e4 < 8; ++e4) {
            float4 a = qs[e4];
            xq[e4*4+0]=a.x; xq[e4*4+1]=a.y; xq[e4*4+2]=a.z; xq[e4*4+3]=a.w;
        }
        float ss = 0.f;
        #pragma unroll
        for (int e = 0; e < 32; ++e) ss += xq[e]*xq[e];
        ss += __shfl_xor(ss, 1);
        float nr = sqrtf(ss);
        float inv = 1.0f / fmaxf(nr, 1e-12f);
        if (!half) nrm_s[r] = nr;

        unsigned int pk[16];
        #pragma unroll
        for (int e = 0; e < 16; ++e)
            pk[e] = pack_trunc(xq[2*e] * inv, xq[2*e+1] * inv);
        char* kb = lds + r * KSTRB + half * 64;
        #pragma unroll
        for (int e4 = 0; e4 < 4; ++e4)
            *(uint4*)(kb + e4*16) = make_uint4(pk[e4*4], pk[e4*4+1], pk[e4*4+2], pk[e4*4+3]);
    }
    // ---- stage V^T packed (dword = 2 consecutive keys) ----
    {
        int a = tid & 63, sub = tid >> 6;     // a = key pair, sub = dim quarter
        int tok0 = tkx[2*a], tok1 = tkx[2*a+1];
        const float4* v0 = (const float4*)(v + ((size_t)b * S + tok0) * D + sub * 16);
        const float4* v1 = (const float4*)(v + ((size_t)b * S + tok1) * D + sub * 16);
        float x0[16], x1[16];
        #pragma unroll
        for (int e4 = 0; e4 < 4; ++e4) {
            float4 p0 = v0[e4], p1 = v1[e4];
            x0[e4*4+0]=p0.x; x0[e4*4+1]=p0.y; x0[e4*4+2]=p0.z; x0[e4*4+3]=p0.w;
            x1[e4*4+0]=p1.x; x1[e4*4+1]=p1.y; x1[e4*4+2]=p1.z; x1[e4*4+3]=p1.w;
        }
        #pragma unroll
        for (int e = 0; e < 16; ++e) {
            int dd = sub * 16 + e;
            VtP[dd * VSTRD + a] = pack_trunc(x0[e], x1[e]);
        }
    }
    __syncthreads();

    int wv   = tid >> 6;
    int lane = tid & 63;
    int quad = lane >> 4;
    int cc   = lane & 15;

    // ---- dots: QK^T via bf16 MFMA ----
    int qrow = wv * 16 + cc;
    f4_t acc[8];
    #pragma unroll
    for (int t = 0; t < 8; ++t) acc[t] = (f4_t){0.f,0.f,0.f,0.f};

    #pragma unroll
    for (int kc = 0; kc < 2; ++kc) {
        int aoff = kc * 64 + quad * 16;
        s8_t av = *(const s8_t*)(lds + qrow * KSTRB + aoff);
        #pragma unroll
        for (int t = 0; t < 8; ++t) {
            s8_t bv = *(const s8_t*)(lds + (t * 16 + cc) * KSTRB + aoff);
            acc[t] = __builtin_amdgcn_mfma_f32_16x16x32_bf16(av, bv, acc[t], 0, 0, 0);
        }
    }

    // ---- scale + self-mask + softmax ----
    int tqi[4];
    float sc[4];
    #pragma unroll
    for (int g = 0; g < 4; ++g) {
        int q = wv * 16 + quad * 4 + g;
        tqi[g] = tkx[q];
        sc[g] = nrm_s[q] * 0.125f;
    }
    int tki[8];
    #pragma unroll
    for (int t = 0; t < 8; ++t) tki[t] = tkx[t * 16 + cc];

    #pragma unroll
    for (int t = 0; t < 8; ++t)
        #pragma unroll
        for (int g = 0; g < 4; ++g) {
            float d = acc[t][g] * sc[g];
            if (tqi[g] == tki[t]) d = -1e5f;
            acc[t][g] = d;
        }

    float mx[4];
    #pragma unroll
    for (int g = 0; g < 4; ++g) {
        float m = acc[0][g];
        #pragma unroll
        for (int t = 1; t < 8; ++t) m = fmaxf(m, acc[t][g]);
        mx[g] = m;
    }
    #pragma unroll
    for (int msk = 1; msk <= 8; msk <<= 1)
        #pragma unroll
        for (int g = 0; g < 4; ++g) mx[g] = fmaxf(mx[g], __shfl_xor(mx[g], msk, 64));

    float sm[4] = {0.f, 0.f, 0.f, 0.f};
    #pragma unroll
    for (int t = 0; t < 8; ++t)
        #pragma unroll
        for (int g = 0; g < 4; ++g) {
            float p = __expf(acc[t][g] - mx[g]);
            acc[t][g] = p;
            sm[g] += p;
        }
    #pragma unroll
    for (int msk = 1; msk <= 8; msk <<= 1)
        #pragma unroll
        for (int g = 0; g < 4; ++g) sm[g] += __shfl_xor(sm[g], msk, 64);

    float pinv[4];
    #pragma unroll
    for (int g = 0; g < 4; ++g) pinv[g] = 1.0f / sm[g];

    if (cc == 0) {
        #pragma unroll
        for (int g = 0; g < 4; ++g)
            logits_ws[sbase + h * S + tqi[g]] = mx[g] + __logf(sm[g]);
    }

    // ---- P -> bf16 into LDS, overlaying K rows 0..63 ----
    __syncthreads();
    #pragma unroll
    for (int t = 0; t < 8; ++t) {
        int key = t * 16 + cc;
        #pragma unroll
        for (int g = 0; g < 4; ++g) {
            int q = wv * 16 + quad * 4 + g;
            *(unsigned short*)(lds + q * KSTRB + key * 2) =
                bf16_trunc(acc[t][g] * pinv[g]);
        }
    }

    // ---- PV via bf16 MFMA (A = own wave's P rows, B = VtP rows) ----
    f4_t oacc[4];
    #pragma unroll
    for (int n = 0; n < 4; ++n) oacc[n] = (f4_t){0.f,0.f,0.f,0.f};

    #pragma unroll
    for (int kc = 0; kc < 4; ++kc) {
        int koff = kc * 64 + quad * 16;   // byte offset: key k at byte 2k
        s8_t pa = *(const s8_t*)(lds + (wv * 16 + cc) * KSTRB + koff);
        #pragma unroll
        for (int n = 0; n < 4; ++n) {
            s8_t bv = *(const s8_t*)((const char*)(VtP + (n * 16 + cc) * VSTRD) + koff);
            oacc[n] = __builtin_amdgcn_mfma_f32_16x16x32_bf16(pa, bv, oacc[n], 0, 0, 0);
        }
    }

    // ---- write O (bf16, truncation) ----
    #pragma unroll
    for (int g = 0; g < 4; ++g) {
        __hip_bfloat16* op = o_ws + ((size_t)(sbase + h * S + tqi[g])) * D;
        #pragma unroll
        for (int n = 0; n < 4; ++n)
            *(unsigned short*)(op + n * 16 + cc) = bf16_trunc(oacc[n][g]);
    }
}

// ---------------------------------------------------------------------------
// Kernel 4: combine hash rounds with softmax(logits) weights. o_ws is bf16.
// ---------------------------------------------------------------------------
__global__ __launch_bounds__(256) void combine_kernel(
    const __hip_bfloat16* __restrict__ o_ws, const float* __restrict__ logits_ws,
    float* __restrict__ out)
{
    int gid = blockIdx.x * 256 + threadIdx.x;
    int token = gid >> 3;          // b*S + t
    int d8 = gid & 7;
    int b = token >> 12;
    int t = token & (S - 1);
    int base = b * (NH * S) + t;

    float l[8];
    #pragma unroll
    for (int hh = 0; hh < 8; ++hh) l[hh] = logits_ws[base + hh * S];
    float m = l[0];
    #pragma unroll
    for (int hh = 1; hh < 8; ++hh) m = fmaxf(m, l[hh]);
    float w[8]; float ssum = 0.f;
    #pragma unroll
    for (int hh = 0; hh < 8; ++hh) { w[hh] = __expf(l[hh] - m); ssum += w[hh]; }
    float inv = 1.0f / ssum;

    float accv[8] = {0,0,0,0,0,0,0,0};
    #pragma unroll
    for (int hh = 0; hh < 8; ++hh) {
        uint4 pk = *(const uint4*)(o_ws + (size_t)(base + hh * S) * D + d8 * 8);
        float wh = w[hh] * inv;
        unsigned int ws_[4] = {pk.x, pk.y, pk.z, pk.w};
        #pragma unroll
        for (int e = 0; e < 4; ++e) {
            float lo = __uint_as_float(ws_[e] << 16);
            float hi = __uint_as_float(ws_[e] & 0xffff0000u);
            accv[2*e]   += wh * lo;
            accv[2*e+1] += wh * hi;
        }
    }
    float4* op = (float4*)(out + (size_t)token * D + d8 * 8);
    op[0] = make_float4(accv[0], accv[1], accv[2], accv[3]);
    op[1] = make_float4(accv[4], accv[5], accv[6], accv[7]);
}

// ---------------------------------------------------------------------------
extern "C" void kernel_launch(void* const* d_in, const int* in_sizes, int n_in,
                              void* d_out, int out_size, void* d_ws, size_t ws_size,
                              hipStream_t stream) {
    const float* qk  = (const float*)d_in[0];
    const float* v   = (const float*)d_in[1];
    const float* rot = (const float*)d_in[2];

    float* out         = (float*)d_out;
    float* out_buckets = out + (size_t)B * S * D;

    int*   bucket_ws = (int*)d_ws;
    int*   st_ws     = bucket_ws + (size_t)B * NH * S;
    float* logits_ws = (float*)(st_ws + (size_t)B * NH * S);
    __hip_bfloat16* o_ws = (__hip_bfloat16*)(logits_ws + (size_t)B * NH * S);

    hash_kernel<<<B * NH * 2, 256, 0, stream>>>(qk, rot, out_buckets, bucket_ws);
    sort_kernel<<<B * NH, 256, 0, stream>>>(bucket_ws, st_ws);
    attn_kernel<<<B * CHUNKS, 256, 0, stream>>>(qk, v, st_ws, o_ws, logits_ws);
    combine_kernel<<<(B * S * 8) / 256, 256, 0, stream>>>(o_ws, logits_ws, out);
}

// Round 7
// 294.511 us; speedup vs baseline: 1.1330x; 1.1330x over previous
//
#include <hip/hip_runtime.h>
#include <hip/hip_bf16.h>
#include <math.h>

// Problem constants
#define B 16
#define S 4096
#define D 64
#define NH 8
#define NBUCK 64          // buckets per hash
#define CHUNKS 512        // chunks per batch (NH * NBUCK)
#define BS 64             // bucket/chunk size

#define GAP_THRESH 4e-3f  // f32 argmax certainty margin (err bound ~1.5e-4)

typedef __attribute__((ext_vector_type(8))) short s8_t;   // 8 bf16 (4 VGPRs)
typedef __attribute__((ext_vector_type(4))) float f4_t;   // MFMA C/D

// truncation-pack two f32 into (bf16(x0) | bf16(x1)<<16): one v_perm_b32
__device__ inline unsigned int pack_trunc(float x0, float x1) {
    return __builtin_amdgcn_perm(__float_as_uint(x1), __float_as_uint(x0),
                                 0x07060302u);
}
__device__ inline unsigned short bf16_trunc(float x) {
    return (unsigned short)(__float_as_uint(x) >> 16);
}

// ---------------------------------------------------------------------------
// Kernel 1: f32 hash pass. 4 tokens/lane x 32 outputs, ONE pass (qk read
// once, coalesced-in-L2 by 4-token amortization). Tracks top-2 of [r,-r];
// tokens with gap < GAP_THRESH are flagged for exact f64 recompute.
// ---------------------------------------------------------------------------
__global__ __launch_bounds__(256, 2) void hash_kernel(
    const float* __restrict__ qk, const float* __restrict__ rot,
    float* __restrict__ out_buckets, int* __restrict__ bucket_ws,
    int* __restrict__ flag_cnt, int* __restrict__ flag_list)
{
    __shared__ float R[64 * 32];   // R[f*32+i], 8 KB
    int tid = threadIdx.x;
    int bid = blockIdx.x;
    int b   = bid >> 5;
    int h   = (bid >> 2) & 7;
    int qtr = bid & 3;

    for (int e = tid; e < 2048; e += 256)
        R[e] = rot[(e >> 5) * (NH * 32) + h * 32 + (e & 31)];
    __syncthreads();

    const float4* rowp[4];
    #pragma unroll
    for (int j = 0; j < 4; ++j) {
        int t = qtr * 1024 + j * 256 + tid;
        rowp[j] = (const float4*)(qk + ((size_t)b * S + t) * D);
    }

    float acc[128];   // acc[i*4+j], i = output 0..31, j = token 0..3
    #pragma unroll
    for (int e = 0; e < 128; ++e) acc[e] = 0.f;

    for (int fc = 0; fc < 16; ++fc) {
        float xf[4][4];
        #pragma unroll
        for (int j = 0; j < 4; ++j) {
            float4 x4 = rowp[j][fc];
            xf[j][0] = x4.x; xf[j][1] = x4.y; xf[j][2] = x4.z; xf[j][3] = x4.w;
        }
        #pragma unroll
        for (int u = 0; u < 4; ++u) {
            int f = fc * 4 + u;
            const float4* Rr = (const float4*)&R[f * 32];
            #pragma unroll
            for (int ii = 0; ii < 8; ++ii) {
                float4 r4 = Rr[ii];
                float rv[4] = {r4.x, r4.y, r4.z, r4.w};
                #pragma unroll
                for (int cpt = 0; cpt < 4; ++cpt) {
                    int i = ii * 4 + cpt;
                    #pragma unroll
                    for (int j = 0; j < 4; ++j)
                        acc[i*4 + j] = __builtin_fmaf(xf[j][u], rv[cpt], acc[i*4 + j]);
                }
            }
        }
    }

    // top-2 tracking per token (best side and worst side)
    float b1v[4], b2v[4], w1v[4], w2v[4];
    int b1i[4], w1i[4];
    #pragma unroll
    for (int j = 0; j < 4; ++j) {
        b1v[j] = acc[j]; b1i[j] = 0; b2v[j] = -1e30f;
        w1v[j] = acc[j]; w1i[j] = 0; w2v[j] =  1e30f;
    }
    #pragma unroll
    for (int i = 1; i < 32; ++i)
        #pragma unroll
        for (int j = 0; j < 4; ++j) {
            float vv = acc[i*4 + j];
            if (vv > b1v[j]) { b2v[j] = b1v[j]; b1v[j] = vv; b1i[j] = i; }
            else if (vv > b2v[j]) b2v[j] = vv;
            if (vv < w1v[j]) { w2v[j] = w1v[j]; w1v[j] = vv; w1i[j] = i; }
            else if (vv < w2v[j]) w2v[j] = vv;
        }

    #pragma unroll
    for (int j = 0; j < 4; ++j) {
        int t = qtr * 1024 + j * 256 + tid;
        size_t idx = (size_t)(b * NH + h) * S + t;
        float v1p = b1v[j], v1n = -w1v[j];
        int bucket; float v1, v2;
        if (v1n > v1p) { bucket = 32 + w1i[j]; v1 = v1n; v2 = fmaxf(v1p, -w2v[j]); }
        else           { bucket = b1i[j];      v1 = v1p; v2 = fmaxf(b2v[j], v1n); }
        bucket_ws[idx] = bucket;
        out_buckets[idx] = (float)(bucket + h * NBUCK);
        if (v1 - v2 < GAP_THRESH) {
            int slot = atomicAdd(flag_cnt, 1);
            flag_list[slot] = (int)idx;
        }
    }
}

// ---------------------------------------------------------------------------
// Kernel 1b: exact f64 recompute for flagged (ambiguous) tokens. ~500 tokens
// expected; decision-equivalent to a full-f64 hash (first-occurrence ties).
// ---------------------------------------------------------------------------
__global__ __launch_bounds__(256) void hash_fixup_kernel(
    const float* __restrict__ qk, const float* __restrict__ rot,
    const int* __restrict__ flag_cnt, const int* __restrict__ flag_list,
    float* __restrict__ out_buckets, int* __restrict__ bucket_ws)
{
    int n = *flag_cnt;
    for (int g = blockIdx.x * 256 + threadIdx.x; g < n; g += gridDim.x * 256) {
        int gid = flag_list[g];
        int bh = gid >> 12, t = gid & (S - 1);
        int b = bh >> 3, h = bh & 7;
        const float* row = qk + ((size_t)b * S + t) * D;

        double acc[32];
        #pragma unroll
        for (int i = 0; i < 32; ++i) acc[i] = 0.0;
        for (int f = 0; f < 64; ++f) {
            double x = (double)row[f];
            const float* rr = rot + f * (NH * 32) + h * 32;
            #pragma unroll
            for (int i = 0; i < 32; ++i)
                acc[i] = __fma_rn(x, (double)rr[i], acc[i]);
        }
        double best = acc[0]; int bi = 0;
        double worst = acc[0]; int wi = 0;
        #pragma unroll
        for (int i = 1; i < 32; ++i) {
            if (acc[i] > best)  { best = acc[i]; bi = i; }
            if (acc[i] < worst) { worst = acc[i]; wi = i; }
        }
        int bucket = (-worst > best) ? (32 + wi) : bi;
        bucket_ws[gid] = bucket;
        out_buckets[gid] = (float)(bucket + h * NBUCK);
    }
}

// ---------------------------------------------------------------------------
// Kernel 2: parallel stable counting sort per (b,h). 256 threads (4 waves).
// ---------------------------------------------------------------------------
__global__ __launch_bounds__(256) void sort_kernel(
    const int* __restrict__ bucket_ws, int* __restrict__ st_ws)
{
    __shared__ int sb[S];
    __shared__ int hist[4][64];
    __shared__ int bpref[64];
    __shared__ int woff[4][64];

    int tid  = threadIdx.x;
    int wv   = tid >> 6;
    int lane = tid & 63;
    int base = blockIdx.x * S;

    hist[wv][lane] = 0;
    __syncthreads();

    int qbase = wv * 1024;
    #pragma unroll
    for (int i = 0; i < 16; ++i) {
        int t = qbase + i * 64 + lane;
        int v = bucket_ws[base + t];
        sb[t] = v;
        atomicAdd(&hist[wv][v], 1);
    }
    __syncthreads();

    if (wv == 0) {
        int total = hist[0][lane] + hist[1][lane] + hist[2][lane] + hist[3][lane];
        int x = total;
        #pragma unroll
        for (int off = 1; off < 64; off <<= 1) {
            int y = __shfl_up(x, off, 64);
            if (lane >= off) x += y;
        }
        bpref[lane] = x - total;
    }
    __syncthreads();
    {
        int o = bpref[lane];
        for (int w2 = 0; w2 < 4; ++w2) {
            if (w2 < wv) o += hist[w2][lane];
        }
        woff[wv][lane] = o;
    }
    __syncthreads();

    for (int g = 0; g < 16; ++g) {
        int t = qbase + g * 64 + lane;
        int v = sb[t];

        unsigned long long m = ~0ULL;
        #pragma unroll
        for (int bit = 0; bit < 6; ++bit) {
            unsigned long long bm = __ballot((v >> bit) & 1);
            m &= ((v >> bit) & 1) ? bm : ~bm;
        }
        unsigned long long below = (lane == 63) ? ~0ULL >> 1
                                 : ((1ULL << lane) - 1ULL);
        int rank = __popcll(m & below);
        int cnt  = __popcll(m);

        int pos = woff[wv][v] + rank;
        st_ws[base + pos] = t;

        if ((m & below) == 0ULL)
            woff[wv][v] += cnt;
        __builtin_amdgcn_s_waitcnt(0);
    }
}

// ---------------------------------------------------------------------------
// Kernel 3: per-chunk attention, plain-bf16 MFMA, truncation-packed converts.
// LDS layout (37888 B -> 4 blocks/CU):
//   K  [128 rows][144 B] @0      (18432)  normalized keys bf16
//                                 -- rows 0..63 overlaid by P[64][144B] post-dots
//   VtP[64 rows][288 B]  @18432  (18432)  V^T packed: dword = keys(2a,2a+1)
//   nrm @36864 (512), tkx @37376 (512)
// ---------------------------------------------------------------------------
#define OFF_VT 18432
#define OFF_NRM 36864
#define OFF_TKX 37376
#define LDS_TOT 37888
#define KSTRB 144     // K/P row stride bytes (72 bf16), 16B-aligned
#define VSTRD 72      // VtP row stride in dwords (288 B)

__global__ __launch_bounds__(256, 4) void attn_kernel(
    const float* __restrict__ qk, const float* __restrict__ v,
    const int* __restrict__ st_ws,
    __hip_bfloat16* __restrict__ o_ws, float* __restrict__ logits_ws)
{
    __shared__ char lds[LDS_TOT];
    float* nrm_s = (float*)(lds + OFF_NRM);
    int*   tkx   = (int*)(lds + OFF_TKX);
    unsigned int* VtP = (unsigned int*)(lds + OFF_VT);

    int tid = threadIdx.x;
    int c = blockIdx.x & (CHUNKS - 1);
    int b = blockIdx.x >> 9;
    int h = c >> 6;
    int sbase = b * (NH * S);

    if (tid < 128) {
        int cc2 = (tid < 64) ? c : ((c + CHUNKS - 1) & (CHUNKS - 1));
        tkx[tid] = st_ws[sbase + cc2 * BS + (tid & 63)];
    }
    __syncthreads();

    // ---- stage K (normalized bf16, row-major) ----
    {
        int r = tid >> 1, half = tid & 1;
        int tok = tkx[r];
        const float4* qs = (const float4*)(qk + ((size_t)b * S + tok) * D) + half * 8;
        float xq[32];
        #pragma unroll
        for (int e4 = 0; e4 < 8; ++e4) {
            float4 a = qs[e4];
            xq[e4*4+0]=a.x; xq[e4*4+1]=a.y; xq[e4*4+2]=a.z; xq[e4*4+3]=a.w;
        }
        float ss = 0.f;
        #pragma unroll
        for (int e = 0; e < 32; ++e) ss += xq[e]*xq[e];
        ss += __shfl_xor(ss, 1);
        float nr = sqrtf(ss);
        float inv = 1.0f / fmaxf(nr, 1e-12f);
        if (!half) nrm_s[r] = nr;

        unsigned int pk[16];
        #pragma unroll
        for (int e = 0; e < 16; ++e)
            pk[e] = pack_trunc(xq[2*e] * inv, xq[2*e+1] * inv);
        char* kb = lds + r * KSTRB + half * 64;
        #pragma unroll
        for (int e4 = 0; e4 < 4; ++e4)
            *(uint4*)(kb + e4*16) = make_uint4(pk[e4*4], pk[e4*4+1], pk[e4*4+2], pk[e4*4+3]);
    }
    // ---- stage V^T packed (dword = 2 consecutive keys) ----
    {
        int a = tid & 63, sub = tid >> 6;     // a = key pair, sub = dim quarter
        int tok0 = tkx[2*a], tok1 = tkx[2*a+1];
        const float4* v0 = (const float4*)(v + ((size_t)b * S + tok0) * D + sub * 16);
        const float4* v1 = (const float4*)(v + ((size_t)b * S + tok1) * D + sub * 16);
        float x0[16], x1[16];
        #pragma unroll
        for (int e4 = 0; e4 < 4; ++e4) {
            float4 p0 = v0[e4], p1 = v1[e4];
            x0[e4*4+0]=p0.x; x0[e4*4+1]=p0.y; x0[e4*4+2]=p0.z; x0[e4*4+3]=p0.w;
            x1[e4*4+0]=p1.x; x1[e4*4+1]=p1.y; x1[e4*4+2]=p1.z; x1[e4*4+3]=p1.w;
        }
        #pragma unroll
        for (int e = 0; e < 16; ++e) {
            int dd = sub * 16 + e;
            VtP[dd * VSTRD + a] = pack_trunc(x0[e], x1[e]);
        }
    }
    __syncthreads();

    int wv   = tid >> 6;
    int lane = tid & 63;
    int quad = lane >> 4;
    int cc   = lane & 15;

    // ---- dots: QK^T via bf16 MFMA ----
    int qrow = wv * 16 + cc;
    f4_t acc[8];
    #pragma unroll
    for (int t = 0; t < 8; ++t) acc[t] = (f4_t){0.f,0.f,0.f,0.f};

    #pragma unroll
    for (int kc = 0; kc < 2; ++kc) {
        int aoff = kc * 64 + quad * 16;
        s8_t av = *(const s8_t*)(lds + qrow * KSTRB + aoff);
        #pragma unroll
        for (int t = 0; t < 8; ++t) {
            s8_t bv = *(const s8_t*)(lds + (t * 16 + cc) * KSTRB + aoff);
            acc[t] = __builtin_amdgcn_mfma_f32_16x16x32_bf16(av, bv, acc[t], 0, 0, 0);
        }
    }

    // ---- scale + self-mask + softmax ----
    int tqi[4];
    float sc[4];
    #pragma unroll
    for (int g = 0; g < 4; ++g) {
        int q = wv * 16 + quad * 4 + g;
        tqi[g] = tkx[q];
        sc[g] = nrm_s[q] * 0.125f;
    }
    int tki[8];
    #pragma unroll
    for (int t = 0; t < 8; ++t) tki[t] = tkx[t * 16 + cc];

    #pragma unroll
    for (int t = 0; t < 8; ++t)
        #pragma unroll
        for (int g = 0; g < 4; ++g) {
            float d = acc[t][g] * sc[g];
            if (tqi[g] == tki[t]) d = -1e5f;
            acc[t][g] = d;
        }

    float mx[4];
    #pragma unroll
    for (int g = 0; g < 4; ++g) {
        float m = acc[0][g];
        #pragma unroll
        for (int t = 1; t < 8; ++t) m = fmaxf(m, acc[t][g]);
        mx[g] = m;
    }
    #pragma unroll
    for (int msk = 1; msk <= 8; msk <<= 1)
        #pragma unroll
        for (int g = 0; g < 4; ++g) mx[g] = fmaxf(mx[g], __shfl_xor(mx[g], msk, 64));

    float sm[4] = {0.f, 0.f, 0.f, 0.f};
    #pragma unroll
    for (int t = 0; t < 8; ++t)
        #pragma unroll
        for (int g = 0; g < 4; ++g) {
            float p = __expf(acc[t][g] - mx[g]);
            acc[t][g] = p;
            sm[g] += p;
        }
    #pragma unroll
    for (int msk = 1; msk <= 8; msk <<= 1)
        #pragma unroll
        for (int g = 0; g < 4; ++g) sm[g] += __shfl_xor(sm[g], msk, 64);

    float pinv[4];
    #pragma unroll
    for (int g = 0; g < 4; ++g) pinv[g] = 1.0f / sm[g];

    if (cc == 0) {
        #pragma unroll
        for (int g = 0; g < 4; ++g)
            logits_ws[sbase + h * S + tqi[g]] = mx[g] + __logf(sm[g]);
    }

    // ---- P -> bf16 into LDS, overlaying K rows 0..63 ----
    __syncthreads();
    #pragma unroll
    for (int t = 0; t < 8; ++t) {
        int key = t * 16 + cc;
        #pragma unroll
        for (int g = 0; g < 4; ++g) {
            int q = wv * 16 + quad * 4 + g;
            *(unsigned short*)(lds + q * KSTRB + key * 2) =
                bf16_trunc(acc[t][g] * pinv[g]);
        }
    }

    // ---- PV via bf16 MFMA (A = own wave's P rows, B = VtP rows) ----
    f4_t oacc[4];
    #pragma unroll
    for (int n = 0; n < 4; ++n) oacc[n] = (f4_t){0.f,0.f,0.f,0.f};

    #pragma unroll
    for (int kc = 0; kc < 4; ++kc) {
        int koff = kc * 64 + quad * 16;   // byte offset: key k at byte 2k
        s8_t pa = *(const s8_t*)(lds + (wv * 16 + cc) * KSTRB + koff);
        #pragma unroll
        for (int n = 0; n < 4; ++n) {
            s8_t bv = *(const s8_t*)((const char*)(VtP + (n * 16 + cc) * VSTRD) + koff);
            oacc[n] = __builtin_amdgcn_mfma_f32_16x16x32_bf16(pa, bv, oacc[n], 0, 0, 0);
        }
    }

    // ---- write O (bf16, truncation) ----
    #pragma unroll
    for (int g = 0; g < 4; ++g) {
        __hip_bfloat16* op = o_ws + ((size_t)(sbase + h * S + tqi[g])) * D;
        #pragma unroll
        for (int n = 0; n < 4; ++n)
            *(unsigned short*)(op + n * 16 + cc) = bf16_trunc(oacc[n][g]);
    }
}

// ---------------------------------------------------------------------------
// Kernel 4: combine hash rounds with softmax(logits) weights. o_ws is bf16.
// ---------------------------------------------------------------------------
__global__ __launch_bounds__(256) void combine_kernel(
    const __hip_bfloat16* __restrict__ o_ws, const float* __restrict__ logits_ws,
    float* __restrict__ out)
{
    int gid = blockIdx.x * 256 + threadIdx.x;
    int token = gid >> 3;          // b*S + t
    int d8 = gid & 7;
    int b = token >> 12;
    int t = token & (S - 1);
    int base = b * (NH * S) + t;

    float l[8];
    #pragma unroll
    for (int hh = 0; hh < 8; ++hh) l[hh] = logits_ws[base + hh * S];
    float m = l[0];
    #pragma unroll
    for (int hh = 1; hh < 8; ++hh) m = fmaxf(m, l[hh]);
    float w[8]; float ssum = 0.f;
    #pragma unroll
    for (int hh = 0; hh < 8; ++hh) { w[hh] = __expf(l[hh] - m); ssum += w[hh]; }
    float inv = 1.0f / ssum;

    float accv[8] = {0,0,0,0,0,0,0,0};
    #pragma unroll
    for (int hh = 0; hh < 8; ++hh) {
        uint4 pk = *(const uint4*)(o_ws + (size_t)(base + hh * S) * D + d8 * 8);
        float wh = w[hh] * inv;
        unsigned int ws_[4] = {pk.x, pk.y, pk.z, pk.w};
        #pragma unroll
        for (int e = 0; e < 4; ++e) {
            float lo = __uint_as_float(ws_[e] << 16);
            float hi = __uint_as_float(ws_[e] & 0xffff0000u);
            accv[2*e]   += wh * lo;
            accv[2*e+1] += wh * hi;
        }
    }
    float4* op = (float4*)(out + (size_t)token * D + d8 * 8);
    op[0] = make_float4(accv[0], accv[1], accv[2], accv[3]);
    op[1] = make_float4(accv[4], accv[5], accv[6], accv[7]);
}

// ---------------------------------------------------------------------------
extern "C" void kernel_launch(void* const* d_in, const int* in_sizes, int n_in,
                              void* d_out, int out_size, void* d_ws, size_t ws_size,
                              hipStream_t stream) {
    const float* qk  = (const float*)d_in[0];
    const float* v   = (const float*)d_in[1];
    const float* rot = (const float*)d_in[2];

    float* out         = (float*)d_out;
    float* out_buckets = out + (size_t)B * S * D;

    int*   bucket_ws = (int*)d_ws;                              // 524288 ints
    int*   st_ws     = bucket_ws + (size_t)B * NH * S;          // 524288 ints
    float* logits_ws = (float*)(st_ws + (size_t)B * NH * S);    // 524288 f32
    __hip_bfloat16* o_ws = (__hip_bfloat16*)(logits_ws + (size_t)B * NH * S); // 64 MB
    int*   flag_cnt  = (int*)(o_ws + (size_t)B * NH * S * D);   // 1 int
    int*   flag_list = flag_cnt + 16;                           // <= 524288 ints

    hipMemsetAsync(flag_cnt, 0, sizeof(int), stream);
    hash_kernel<<<B * NH * 4, 256, 0, stream>>>(qk, rot, out_buckets, bucket_ws,
                                                flag_cnt, flag_list);
    hash_fixup_kernel<<<64, 256, 0, stream>>>(qk, rot, flag_cnt, flag_list,
                                              out_buckets, bucket_ws);
    sort_kernel<<<B * NH, 256, 0, stream>>>(bucket_ws, st_ws);
    attn_kernel<<<B * CHUNKS, 256, 0, stream>>>(qk, v, st_ws, o_ws, logits_ws);
    combine_kernel<<<(B * S * 8) / 256, 256, 0, stream>>>(o_ws, logits_ws, out);
}